// Round 1
// baseline (65.235 us; speedup 1.0000x reference)
//
#include <hip/hip_runtime.h>
#include <math.h>

#define T_SEQ 512
#define B_SZ  64
#define HDIM  768
#define NROWS (B_SZ * T_SEQ)
#define NEGI  (-1e30f)

// ---------------------------------------------------------------------------
// Kernel 1: fused  z_t = x@w_normal+b_n,  z_s = x@w_upper+b_u,
//           p = softmax(z_t), alpha = 0.5*sum(p^2),
//           z_s_tilde = (z_t@w_trans)*alpha + z_s*(1-alpha)
// One wave per row (row = b*T + t). Fully coalesced float4 x loads,
// per-lane weight fragments in registers, butterfly reduce.
// ---------------------------------------------------------------------------
__global__ __launch_bounds__(256) void k1_fused_linear(
    const float* __restrict__ x,
    const float* __restrict__ w_normal, const float* __restrict__ b_normal,
    const float* __restrict__ w_upper,  const float* __restrict__ b_upper,
    const float* __restrict__ w_trans,
    float* __restrict__ zst_out,   // [NROWS][7]
    float* __restrict__ zt_out)    // [NROWS][3]
{
    const int lane = threadIdx.x & 63;
    const int wid  = blockIdx.x * (blockDim.x >> 6) + (threadIdx.x >> 6);
    const int nw   = gridDim.x * (blockDim.x >> 6);

    // per-lane weight fragments: h = i*256 + lane*4 + j
    float wN[3][4][3];
    float wU[3][4][7];
#pragma unroll
    for (int i = 0; i < 3; ++i) {
#pragma unroll
        for (int j = 0; j < 4; ++j) {
            const int h = i * 256 + lane * 4 + j;
#pragma unroll
            for (int k = 0; k < 3; ++k) wN[i][j][k] = w_normal[h * 3 + k];
#pragma unroll
            for (int k = 0; k < 7; ++k) wU[i][j][k] = w_upper[h * 7 + k];
        }
    }
    float bn[3], bu[7], wt[3][7];
#pragma unroll
    for (int k = 0; k < 3; ++k) bn[k] = b_normal[k];
#pragma unroll
    for (int k = 0; k < 7; ++k) bu[k] = b_upper[k];
#pragma unroll
    for (int j = 0; j < 3; ++j)
#pragma unroll
        for (int k = 0; k < 7; ++k) wt[j][k] = w_trans[j * 7 + k];

    for (int row = wid; row < NROWS; row += nw) {
        const float4* xp = reinterpret_cast<const float4*>(x + (size_t)row * HDIM);
        float acc[10];
#pragma unroll
        for (int k = 0; k < 10; ++k) acc[k] = 0.f;
#pragma unroll
        for (int i = 0; i < 3; ++i) {
            const float4 v = xp[i * 64 + lane];
            const float xs0 = v.x, xs1 = v.y, xs2 = v.z, xs3 = v.w;
#pragma unroll
            for (int k = 0; k < 3; ++k) {
                acc[k] += xs0 * wN[i][0][k];
                acc[k] += xs1 * wN[i][1][k];
                acc[k] += xs2 * wN[i][2][k];
                acc[k] += xs3 * wN[i][3][k];
            }
#pragma unroll
            for (int k = 0; k < 7; ++k) {
                acc[3 + k] += xs0 * wU[i][0][k];
                acc[3 + k] += xs1 * wU[i][1][k];
                acc[3 + k] += xs2 * wU[i][2][k];
                acc[3 + k] += xs3 * wU[i][3][k];
            }
        }
        // butterfly reduce across 64 lanes: every lane ends with full sums
#pragma unroll
        for (int off = 32; off >= 1; off >>= 1) {
#pragma unroll
            for (int k = 0; k < 10; ++k)
                acc[k] += __shfl_xor(acc[k], off, 64);
        }
        const float zt0 = acc[0] + bn[0];
        const float zt1 = acc[1] + bn[1];
        const float zt2 = acc[2] + bn[2];
        const float mx = fmaxf(zt0, fmaxf(zt1, zt2));
        const float e0 = __expf(zt0 - mx);
        const float e1 = __expf(zt1 - mx);
        const float e2 = __expf(zt2 - mx);
        const float inv = 1.0f / (e0 + e1 + e2);
        const float p0 = e0 * inv, p1 = e1 * inv, p2 = e2 * inv;
        const float alpha = 0.5f * (p0 * p0 + p1 * p1 + p2 * p2);
        const float oma = 1.0f - alpha;
        float zst[7];
#pragma unroll
        for (int k = 0; k < 7; ++k) {
            const float zs  = acc[3 + k] + bu[k];
            const float zsp = zt0 * wt[0][k] + zt1 * wt[1][k] + zt2 * wt[2][k];
            zst[k] = zsp * alpha + zs * oma;
        }
        // static-index select (avoid scratch) then predicated scalar stores
        float vsel = zst[0];
#pragma unroll
        for (int k = 1; k < 7; ++k) vsel = (lane == k) ? zst[k] : vsel;
        if (lane < 7) zst_out[(size_t)row * 7 + lane] = vsel;
        const float vt = (lane == 8) ? zt1 : ((lane == 9) ? zt2 : zt0);
        if (lane >= 7 && lane < 10) zt_out[(size_t)row * 3 + (lane - 7)] = vt;
    }
}

// ---------------------------------------------------------------------------
// Kernel 2: level-1 of the CRF parallel scan.
// Steps t=1..511 split into 64 chunks of 8. One lane computes row `irow` of
// the chunk's log-semiring transfer-matrix product, fully in-register.
// Masked steps act as identity (skip).
// ---------------------------------------------------------------------------
template <int K>
__device__ __forceinline__ void crf_chunk(
    const float* __restrict__ e_base,  // [T_SEQ][K] emissions for batch b
    const int*   __restrict__ mask,    // [T_SEQ] for batch b
    const float* __restrict__ trans,   // [K*K]
    int c, int irow,
    float* __restrict__ outrow)        // K floats
{
    float tr[K][K];
#pragma unroll
    for (int i = 0; i < K; ++i)
#pragma unroll
        for (int j = 0; j < K; ++j) tr[i][j] = trans[i * K + j];

    float a[K];
#pragma unroll
    for (int j = 0; j < K; ++j) a[j] = (j == irow) ? 0.f : NEGI;

    const int t0 = 1 + c * 8;
    int t1 = t0 + 8;
    if (t1 > T_SEQ) t1 = T_SEQ;
    for (int t = t0; t < t1; ++t) {
        if (mask[t]) {
            float e[K];
#pragma unroll
            for (int j = 0; j < K; ++j) e[j] = e_base[t * K + j];
            float na[K];
#pragma unroll
            for (int j = 0; j < K; ++j) {
                float m = a[0] + tr[0][j];
#pragma unroll
                for (int i = 1; i < K; ++i) m = fmaxf(m, a[i] + tr[i][j]);
                float s = 0.f;
#pragma unroll
                for (int i = 0; i < K; ++i) s += __expf(a[i] + tr[i][j] - m);
                na[j] = e[j] + m + __logf(s);
            }
#pragma unroll
            for (int j = 0; j < K; ++j) a[j] = na[j];
        }
    }
#pragma unroll
    for (int j = 0; j < K; ++j) outrow[j] = a[j];
}

__global__ __launch_bounds__(256) void k2_chunks(
    const float* __restrict__ zst, const float* __restrict__ zt,
    const int* __restrict__ mask,
    const float* __restrict__ trans_s, const float* __restrict__ trans_n,
    float* __restrict__ M7, float* __restrict__ M3)
{
    const int tid = blockIdx.x * 256 + threadIdx.x;
    const int N7 = B_SZ * 64 * 7;
    if (tid < N7) {
        const int i = tid % 7;
        const int c = (tid / 7) & 63;
        const int b = tid / (7 * 64);
        crf_chunk<7>(zst + (size_t)b * T_SEQ * 7, mask + b * T_SEQ, trans_s,
                     c, i, M7 + ((size_t)(b * 64 + c) * 7 + i) * 7);
    } else if (tid < N7 + B_SZ * 64 * 3) {
        const int r = tid - N7;
        const int i = r % 3;
        const int c = (r / 3) & 63;
        const int b = r / (3 * 64);
        crf_chunk<3>(zt + (size_t)b * T_SEQ * 3, mask + b * T_SEQ, trans_n,
                     c, i, M3 + ((size_t)(b * 64 + c) * 3 + i) * 3);
    }
}

// ---------------------------------------------------------------------------
// Kernel 3: per (b, crf): tree-combine the 64 chunk matrices in LDS,
// compute logZ = LSE_{i,j}(alpha0[i] + M[i][j] + end[j]) with
// alpha0 = start + emissions[0]; plus the gold-path score; write partial.
// ---------------------------------------------------------------------------
template <int K>
__device__ void combine_and_score(
    const float* __restrict__ M,       // [64][K*K] for this b
    const float* __restrict__ z,       // [T_SEQ][K] emissions for this b
    const int*   __restrict__ mask,    // [T_SEQ]
    const int*   __restrict__ labels,  // [T_SEQ]
    const float* __restrict__ trans, const float* __restrict__ startv,
    const float* __restrict__ endv,
    float* __restrict__ out_partial,
    float* bufA, float* bufB, float* red, float* redm)
{
    const int tid = threadIdx.x;
    const int KK = K * K;
    for (int idx = tid; idx < 64 * KK; idx += 256) bufA[idx] = M[idx];
    __syncthreads();

    float* src = bufA;
    float* dst = bufB;
    int n = 64;
    while (n > 1) {
        const int half = n >> 1;
        const int tasks = half * KK;
        for (int task = tid; task < tasks; task += 256) {
            const int p = task / KK;
            const int ij = task % KK;
            const int i = ij / K, j = ij % K;
            const float* A  = src + (size_t)(2 * p) * KK;
            const float* Bm = src + (size_t)(2 * p + 1) * KK;
            float m = A[i * K + 0] + Bm[0 * K + j];
#pragma unroll
            for (int k = 1; k < K; ++k) m = fmaxf(m, A[i * K + k] + Bm[k * K + j]);
            float s = 0.f;
#pragma unroll
            for (int k = 0; k < K; ++k) s += __expf(A[i * K + k] + Bm[k * K + j] - m);
            dst[task] = m + __logf(s);
        }
        __syncthreads();
        float* tmp = src; src = dst; dst = tmp;
        n = half;
    }
    // src[0..KK) = product over t=1..511

    // gold-path score pieces (emit + trans) and mask count
    float local_s = 0.f, local_m = 0.f;
    for (int t = tid; t < T_SEQ; t += 256) {
        const float mf = (float)mask[t];
        const int tg = labels[t];
        local_s += mf * z[t * K + tg];
        local_m += mf;
        if (t >= 1) {
            const int tp = labels[t - 1];
            local_s += mf * trans[tp * K + tg];
        }
    }
    red[tid] = local_s;
    redm[tid] = local_m;
    __syncthreads();
    for (int s = 128; s >= 1; s >>= 1) {
        if (tid < s) { red[tid] += red[tid + s]; redm[tid] += redm[tid + s]; }
        __syncthreads();
    }
    if (tid == 0) {
        float score = red[0];
        const int nvalid = (int)(redm[0] + 0.5f);
        const int last = nvalid - 1;
        score += startv[labels[0]] + endv[labels[last]];

        float alpha0[K];
#pragma unroll
        for (int i = 0; i < K; ++i) alpha0[i] = startv[i] + z[i];
        float v[K];
#pragma unroll
        for (int j = 0; j < K; ++j) {
            float m = alpha0[0] + src[0 * K + j];
#pragma unroll
            for (int i = 1; i < K; ++i) m = fmaxf(m, alpha0[i] + src[i * K + j]);
            float s = 0.f;
#pragma unroll
            for (int i = 0; i < K; ++i) s += __expf(alpha0[i] + src[i * K + j] - m);
            v[j] = m + __logf(s) + endv[j];
        }
        float mm = v[0];
#pragma unroll
        for (int j = 1; j < K; ++j) mm = fmaxf(mm, v[j]);
        float ss = 0.f;
#pragma unroll
        for (int j = 0; j < K; ++j) ss += __expf(v[j] - mm);
        const float logZ = mm + __logf(ss);
        out_partial[0] = score - logZ;
    }
}

__global__ __launch_bounds__(256) void k3_combine(
    const float* __restrict__ M7, const float* __restrict__ M3,
    const float* __restrict__ zst, const float* __restrict__ zt,
    const int* __restrict__ mask, const int* __restrict__ labels,
    const int* __restrict__ labels_n,
    const float* __restrict__ trans_s, const float* __restrict__ start_s,
    const float* __restrict__ end_s,
    const float* __restrict__ trans_n, const float* __restrict__ start_n,
    const float* __restrict__ end_n,
    float* __restrict__ partials)
{
    __shared__ float bufA[64 * 49];
    __shared__ float bufB[32 * 49];
    __shared__ float red[256];
    __shared__ float redm[256];
    const int b = blockIdx.x & 63;
    if (blockIdx.x < 64) {
        combine_and_score<3>(M3 + (size_t)b * 64 * 9, zt + (size_t)b * T_SEQ * 3,
                             mask + b * T_SEQ, labels_n + b * T_SEQ,
                             trans_n, start_n, end_n, partials + blockIdx.x,
                             bufA, bufB, red, redm);
    } else {
        combine_and_score<7>(M7 + (size_t)b * 64 * 49, zst + (size_t)b * T_SEQ * 7,
                             mask + b * T_SEQ, labels + b * T_SEQ,
                             trans_s, start_s, end_s, partials + blockIdx.x,
                             bufA, bufB, red, redm);
    }
}

// ---------------------------------------------------------------------------
// Kernel 4: loss = -sum(partials[0..127])
// ---------------------------------------------------------------------------
__global__ __launch_bounds__(128) void k4_reduce(const float* __restrict__ partials,
                                                 float* __restrict__ out0)
{
    __shared__ float red[128];
    const int tid = threadIdx.x;
    red[tid] = partials[tid];
    __syncthreads();
    for (int s = 64; s >= 1; s >>= 1) {
        if (tid < s) red[tid] += red[tid + s];
        __syncthreads();
    }
    if (tid == 0) out0[0] = -red[0];
}

// ---------------------------------------------------------------------------
extern "C" void kernel_launch(void* const* d_in, const int* in_sizes, int n_in,
                              void* d_out, int out_size, void* d_ws, size_t ws_size,
                              hipStream_t stream)
{
    const float* x        = (const float*)d_in[0];
    const int*   mask     = (const int*)d_in[1];
    const int*   labels   = (const int*)d_in[2];
    const int*   labels_n = (const int*)d_in[3];
    const float* w_normal = (const float*)d_in[4];
    const float* b_normal = (const float*)d_in[5];
    const float* w_upper  = (const float*)d_in[6];
    const float* b_upper  = (const float*)d_in[7];
    const float* trans_n  = (const float*)d_in[8];
    const float* start_n  = (const float*)d_in[9];
    const float* end_n    = (const float*)d_in[10];
    const float* trans_s  = (const float*)d_in[11];
    const float* start_s  = (const float*)d_in[12];
    const float* end_s    = (const float*)d_in[13];
    const float* w_trans  = (const float*)d_in[14];

    float* out      = (float*)d_out;
    float* loss_out = out;       // [1]
    float* zst      = out + 1;   // [B*T*7]

    float* ws       = (float*)d_ws;
    float* zt       = ws;                              // 98304 floats
    float* M7       = ws + 98304;                      // 200704 floats
    float* M3       = ws + 98304 + 200704;             // 36864 floats
    float* partials = ws + 98304 + 200704 + 36864;     // 128 floats

    k1_fused_linear<<<2048, 256, 0, stream>>>(x, w_normal, b_normal, w_upper,
                                              b_upper, w_trans, zst, zt);
    k2_chunks<<<160, 256, 0, stream>>>(zst, zt, mask, trans_s, trans_n, M7, M3);
    k3_combine<<<128, 256, 0, stream>>>(M7, M3, zst, zt, mask, labels, labels_n,
                                        trans_s, start_s, end_s,
                                        trans_n, start_n, end_n, partials);
    k4_reduce<<<1, 128, 0, stream>>>(partials, loss_out);
}

// Round 2
// 64.812 us; speedup vs baseline: 1.0065x; 1.0065x over previous
//
#include <hip/hip_runtime.h>
#include <math.h>

#define T_SEQ 512
#define B_SZ  64
#define HDIM  768
#define NROWS (B_SZ * T_SEQ)
#define NEGI  (-1e30f)

#define K1_BLOCKS 512
#define K1_WAVES  (K1_BLOCKS * 4)          // 2048 waves, exactly resident at 2/SIMD
#define ROWS_PER_WAVE (NROWS / K1_WAVES)   // 16

// ---------------------------------------------------------------------------
// Kernel 1: fused z_t / z_s / softmax / alpha / z_s_tilde.
// One wave per row; weights staged block-wide in LDS then held in per-lane
// registers; 2-row software pipeline on the streaming x loads.
// ---------------------------------------------------------------------------
__global__ __launch_bounds__(256, 2) void k1_fused_linear(
    const float* __restrict__ x,
    const float* __restrict__ w_normal, const float* __restrict__ b_normal,
    const float* __restrict__ w_upper,  const float* __restrict__ b_upper,
    const float* __restrict__ w_trans,
    float* __restrict__ zst_out,   // [NROWS][7]
    float* __restrict__ zt_out)    // [NROWS][3]
{
    __shared__ float sW[7680];     // wN [768][3] | wU [768][7]
    const int tid = threadIdx.x;
    for (int i = tid; i < 2304; i += 256) sW[i] = w_normal[i];
    for (int i = tid; i < 5376; i += 256) sW[2304 + i] = w_upper[i];
    __syncthreads();

    const int lane = tid & 63;
    const int wid  = blockIdx.x * 4 + (tid >> 6);

    // per-lane weight fragments from LDS (one-time)
    float wN[3][4][3];
    float wU[3][4][7];
#pragma unroll
    for (int i = 0; i < 3; ++i) {
#pragma unroll
        for (int j = 0; j < 4; ++j) {
            const int h = i * 256 + lane * 4 + j;
#pragma unroll
            for (int k = 0; k < 3; ++k) wN[i][j][k] = sW[h * 3 + k];
#pragma unroll
            for (int k = 0; k < 7; ++k) wU[i][j][k] = sW[2304 + h * 7 + k];
        }
    }
    float bn[3], bu[7], wt[3][7];
#pragma unroll
    for (int k = 0; k < 3; ++k) bn[k] = b_normal[k];      // broadcast loads
#pragma unroll
    for (int k = 0; k < 7; ++k) bu[k] = b_upper[k];
#pragma unroll
    for (int j = 0; j < 3; ++j)
#pragma unroll
        for (int k = 0; k < 7; ++k) wt[j][k] = w_trans[j * 7 + k];

    int row = wid;
    float4 cur[3];
    {
        const float4* xp = reinterpret_cast<const float4*>(x + (size_t)row * HDIM);
        cur[0] = xp[lane]; cur[1] = xp[64 + lane]; cur[2] = xp[128 + lane];
    }

#pragma unroll 1
    for (int it = 0; it < ROWS_PER_WAVE; ++it) {
        const int nrow = row + K1_WAVES;
        float4 nxt[3];
        if (it + 1 < ROWS_PER_WAVE) {
            const float4* np = reinterpret_cast<const float4*>(x + (size_t)nrow * HDIM);
            nxt[0] = np[lane]; nxt[1] = np[64 + lane]; nxt[2] = np[128 + lane];
        } else {
            nxt[0] = cur[0]; nxt[1] = cur[1]; nxt[2] = cur[2];
        }

        float acc[10];
#pragma unroll
        for (int k = 0; k < 10; ++k) acc[k] = 0.f;
#pragma unroll
        for (int i = 0; i < 3; ++i) {
            const float xs0 = cur[i].x, xs1 = cur[i].y, xs2 = cur[i].z, xs3 = cur[i].w;
#pragma unroll
            for (int k = 0; k < 3; ++k) {
                acc[k] += xs0 * wN[i][0][k];
                acc[k] += xs1 * wN[i][1][k];
                acc[k] += xs2 * wN[i][2][k];
                acc[k] += xs3 * wN[i][3][k];
            }
#pragma unroll
            for (int k = 0; k < 7; ++k) {
                acc[3 + k] += xs0 * wU[i][0][k];
                acc[3 + k] += xs1 * wU[i][1][k];
                acc[3 + k] += xs2 * wU[i][2][k];
                acc[3 + k] += xs3 * wU[i][3][k];
            }
        }
        // butterfly reduce across 64 lanes
#pragma unroll
        for (int off = 32; off >= 1; off >>= 1) {
#pragma unroll
            for (int k = 0; k < 10; ++k)
                acc[k] += __shfl_xor(acc[k], off, 64);
        }
        const float zt0 = acc[0] + bn[0];
        const float zt1 = acc[1] + bn[1];
        const float zt2 = acc[2] + bn[2];
        const float mx = fmaxf(zt0, fmaxf(zt1, zt2));
        const float e0 = __expf(zt0 - mx);
        const float e1 = __expf(zt1 - mx);
        const float e2 = __expf(zt2 - mx);
        const float inv = 1.0f / (e0 + e1 + e2);
        const float p0 = e0 * inv, p1 = e1 * inv, p2 = e2 * inv;
        const float alpha = 0.5f * (p0 * p0 + p1 * p1 + p2 * p2);
        const float oma = 1.0f - alpha;
        float zst[7];
#pragma unroll
        for (int k = 0; k < 7; ++k) {
            const float zs  = acc[3 + k] + bu[k];
            const float zsp = zt0 * wt[0][k] + zt1 * wt[1][k] + zt2 * wt[2][k];
            zst[k] = zsp * alpha + zs * oma;
        }
        float vsel = zst[0];
#pragma unroll
        for (int k = 1; k < 7; ++k) vsel = (lane == k) ? zst[k] : vsel;
        if (lane < 7) zst_out[(size_t)row * 7 + lane] = vsel;
        const float vt = (lane == 8) ? zt1 : ((lane == 9) ? zt2 : zt0);
        if (lane >= 7 && lane < 10) zt_out[(size_t)row * 3 + (lane - 7)] = vt;

        cur[0] = nxt[0]; cur[1] = nxt[1]; cur[2] = nxt[2];
        row = nrow;
    }
}

// ---------------------------------------------------------------------------
// Kernel 2: one block per (b, crf). Phase A: 64-chunk log-semiring scans into
// LDS. Phase B: tree combine. Phase C: gold score + logZ, atomicAdd into loss.
// ---------------------------------------------------------------------------
template <int K>
__device__ void crf_block(
    const float* __restrict__ z,       // [T_SEQ][K] emissions for this b
    const int*   __restrict__ mask,    // [T_SEQ]
    const int*   __restrict__ labels,  // [T_SEQ]
    const float* __restrict__ trans, const float* __restrict__ startv,
    const float* __restrict__ endv,
    float* __restrict__ loss,
    float* bufA, float* bufB, float* red, float* redm)
{
    const int tid = threadIdx.x;
    const int KK = K * K;

    // ---- Phase A: chunk scans (t = 1 + 8c .. min(+8, 512)) ----
    for (int task = tid; task < 64 * K; task += 256) {
        const int c = task / K;
        const int irow = task % K;
        float E[K][K];
#pragma unroll
        for (int i = 0; i < K; ++i)
#pragma unroll
            for (int j = 0; j < K; ++j) E[i][j] = __expf(trans[i * K + j]);
        float a[K];
#pragma unroll
        for (int j = 0; j < K; ++j) a[j] = (j == irow) ? 0.f : NEGI;
        const int t0 = 1 + c * 8;
        int t1 = t0 + 8;
        if (t1 > T_SEQ) t1 = T_SEQ;
        for (int t = t0; t < t1; ++t) {
            if (mask[t]) {
                float m = a[0];
#pragma unroll
                for (int i = 1; i < K; ++i) m = fmaxf(m, a[i]);
                float ea[K];
#pragma unroll
                for (int i = 0; i < K; ++i) ea[i] = __expf(a[i] - m);
                float na[K];
#pragma unroll
                for (int j = 0; j < K; ++j) {
                    float s = 0.f;
#pragma unroll
                    for (int i = 0; i < K; ++i) s += ea[i] * E[i][j];
                    na[j] = z[t * K + j] + m + __logf(s);
                }
#pragma unroll
                for (int j = 0; j < K; ++j) a[j] = na[j];
            }
        }
#pragma unroll
        for (int j = 0; j < K; ++j) bufA[c * KK + irow * K + j] = a[j];
    }
    __syncthreads();

    // ---- Phase B: tree combine 64 matrices -> 1 ----
    float* src = bufA;
    float* dst = bufB;
    int n = 64;
    while (n > 1) {
        const int half = n >> 1;
        const int tasks = half * KK;
        for (int task = tid; task < tasks; task += 256) {
            const int p = task / KK;
            const int ij = task % KK;
            const int i = ij / K, j = ij % K;
            const float* A  = src + (size_t)(2 * p) * KK;
            const float* Bm = src + (size_t)(2 * p + 1) * KK;
            float m = A[i * K + 0] + Bm[0 * K + j];
#pragma unroll
            for (int k = 1; k < K; ++k) m = fmaxf(m, A[i * K + k] + Bm[k * K + j]);
            float s = 0.f;
#pragma unroll
            for (int k = 0; k < K; ++k) s += __expf(A[i * K + k] + Bm[k * K + j] - m);
            dst[task] = m + __logf(s);
        }
        __syncthreads();
        float* tmp = src; src = dst; dst = tmp;
        n = half;
    }

    // ---- Phase C: gold-path score + logZ ----
    float local_s = 0.f, local_m = 0.f;
    for (int t = tid; t < T_SEQ; t += 256) {
        const float mf = (float)mask[t];
        const int tg = labels[t];
        local_s += mf * z[t * K + tg];
        local_m += mf;
        if (t >= 1) {
            const int tp = labels[t - 1];
            local_s += mf * trans[tp * K + tg];
        }
    }
    red[tid] = local_s;
    redm[tid] = local_m;
    __syncthreads();
    for (int s = 128; s >= 1; s >>= 1) {
        if (tid < s) { red[tid] += red[tid + s]; redm[tid] += redm[tid + s]; }
        __syncthreads();
    }
    if (tid == 0) {
        float score = red[0];
        const int nvalid = (int)(redm[0] + 0.5f);
        const int last = nvalid - 1;
        score += startv[labels[0]] + endv[labels[last]];

        float alpha0[K];
#pragma unroll
        for (int i = 0; i < K; ++i) alpha0[i] = startv[i] + z[i];
        float v[K];
#pragma unroll
        for (int j = 0; j < K; ++j) {
            float m = alpha0[0] + src[0 * K + j];
#pragma unroll
            for (int i = 1; i < K; ++i) m = fmaxf(m, alpha0[i] + src[i * K + j]);
            float s = 0.f;
#pragma unroll
            for (int i = 0; i < K; ++i) s += __expf(alpha0[i] + src[i * K + j] - m);
            v[j] = m + __logf(s) + endv[j];
        }
        float mm = v[0];
#pragma unroll
        for (int j = 1; j < K; ++j) mm = fmaxf(mm, v[j]);
        float ss = 0.f;
#pragma unroll
        for (int j = 0; j < K; ++j) ss += __expf(v[j] - mm);
        const float logZ = mm + __logf(ss);
        atomicAdd(loss, logZ - score);   // loss = -sum(score - logZ)
    }
}

__global__ __launch_bounds__(256) void k2_crf(
    const float* __restrict__ zst, const float* __restrict__ zt,
    const int* __restrict__ mask, const int* __restrict__ labels,
    const int* __restrict__ labels_n,
    const float* __restrict__ trans_s, const float* __restrict__ start_s,
    const float* __restrict__ end_s,
    const float* __restrict__ trans_n, const float* __restrict__ start_n,
    const float* __restrict__ end_n,
    float* __restrict__ loss)
{
    __shared__ float bufA[64 * 49];
    __shared__ float bufB[32 * 49];
    __shared__ float red[256];
    __shared__ float redm[256];
    const int b = blockIdx.x & 63;
    if (blockIdx.x < 64) {
        crf_block<3>(zt + (size_t)b * T_SEQ * 3, mask + b * T_SEQ,
                     labels_n + b * T_SEQ, trans_n, start_n, end_n,
                     loss, bufA, bufB, red, redm);
    } else {
        crf_block<7>(zst + (size_t)b * T_SEQ * 7, mask + b * T_SEQ,
                     labels + b * T_SEQ, trans_s, start_s, end_s,
                     loss, bufA, bufB, red, redm);
    }
}

// ---------------------------------------------------------------------------
extern "C" void kernel_launch(void* const* d_in, const int* in_sizes, int n_in,
                              void* d_out, int out_size, void* d_ws, size_t ws_size,
                              hipStream_t stream)
{
    const float* x        = (const float*)d_in[0];
    const int*   mask     = (const int*)d_in[1];
    const int*   labels   = (const int*)d_in[2];
    const int*   labels_n = (const int*)d_in[3];
    const float* w_normal = (const float*)d_in[4];
    const float* b_normal = (const float*)d_in[5];
    const float* w_upper  = (const float*)d_in[6];
    const float* b_upper  = (const float*)d_in[7];
    const float* trans_n  = (const float*)d_in[8];
    const float* start_n  = (const float*)d_in[9];
    const float* end_n    = (const float*)d_in[10];
    const float* trans_s  = (const float*)d_in[11];
    const float* start_s  = (const float*)d_in[12];
    const float* end_s    = (const float*)d_in[13];
    const float* w_trans  = (const float*)d_in[14];

    float* out      = (float*)d_out;
    float* loss_out = out;       // [1]
    float* zst      = out + 1;   // [B*T*7]
    float* zt       = (float*)d_ws;  // [B*T*3]

    hipMemsetAsync(loss_out, 0, sizeof(float), stream);

    k1_fused_linear<<<K1_BLOCKS, 256, 0, stream>>>(x, w_normal, b_normal,
                                                   w_upper, b_upper, w_trans,
                                                   zst, zt);
    k2_crf<<<128, 256, 0, stream>>>(zst, zt, mask, labels, labels_n,
                                    trans_s, start_s, end_s,
                                    trans_n, start_n, end_n, loss_out);
}

// Round 3
// 59.982 us; speedup vs baseline: 1.0876x; 1.0805x over previous
//
#include <hip/hip_runtime.h>
#include <math.h>

#define T_SEQ 512
#define B_SZ  64
#define HDIM  768
#define NROWS (B_SZ * T_SEQ)
#define NEGI  (-1e30f)

#define K1_BLOCKS 512
#define K1_WAVES  (K1_BLOCKS * 4)          // 2048 waves, resident at 2/SIMD
#define ROWS_PER_WAVE (NROWS / K1_WAVES)   // 16

// ---------------------------------------------------------------------------
// Kernel 1: fused z_t / z_s / softmax / alpha / z_s_tilde.
// One wave per row; weights staged block-wide in LDS then held in per-lane
// registers; 2-row software pipeline on the streaming x loads.
// Also zero-initializes the loss scalar (replaces a memset graph node).
// ---------------------------------------------------------------------------
__global__ __launch_bounds__(256, 2) void k1_fused_linear(
    const float* __restrict__ x,
    const float* __restrict__ w_normal, const float* __restrict__ b_normal,
    const float* __restrict__ w_upper,  const float* __restrict__ b_upper,
    const float* __restrict__ w_trans,
    float* __restrict__ zst_out,   // [NROWS][7]
    float* __restrict__ zt_out,    // [NROWS][3]
    float* __restrict__ loss_out)  // [1] zeroed here, accumulated by k2
{
    if (blockIdx.x == 0 && threadIdx.x == 0) loss_out[0] = 0.f;

    __shared__ float sW[7680];     // wN [768][3] | wU [768][7]
    const int tid = threadIdx.x;
    for (int i = tid; i < 2304; i += 256) sW[i] = w_normal[i];
    for (int i = tid; i < 5376; i += 256) sW[2304 + i] = w_upper[i];
    __syncthreads();

    const int lane = tid & 63;
    const int wid  = blockIdx.x * 4 + (tid >> 6);

    float wN[3][4][3];
    float wU[3][4][7];
#pragma unroll
    for (int i = 0; i < 3; ++i) {
#pragma unroll
        for (int j = 0; j < 4; ++j) {
            const int h = i * 256 + lane * 4 + j;
#pragma unroll
            for (int k = 0; k < 3; ++k) wN[i][j][k] = sW[h * 3 + k];
#pragma unroll
            for (int k = 0; k < 7; ++k) wU[i][j][k] = sW[2304 + h * 7 + k];
        }
    }
    float bn[3], bu[7], wt[3][7];
#pragma unroll
    for (int k = 0; k < 3; ++k) bn[k] = b_normal[k];
#pragma unroll
    for (int k = 0; k < 7; ++k) bu[k] = b_upper[k];
#pragma unroll
    for (int j = 0; j < 3; ++j)
#pragma unroll
        for (int k = 0; k < 7; ++k) wt[j][k] = w_trans[j * 7 + k];

    int row = wid;
    float4 cur[3];
    {
        const float4* xp = reinterpret_cast<const float4*>(x + (size_t)row * HDIM);
        cur[0] = xp[lane]; cur[1] = xp[64 + lane]; cur[2] = xp[128 + lane];
    }

#pragma unroll 1
    for (int it = 0; it < ROWS_PER_WAVE; ++it) {
        const int nrow = row + K1_WAVES;
        float4 nxt[3];
        if (it + 1 < ROWS_PER_WAVE) {
            const float4* np = reinterpret_cast<const float4*>(x + (size_t)nrow * HDIM);
            nxt[0] = np[lane]; nxt[1] = np[64 + lane]; nxt[2] = np[128 + lane];
        } else {
            nxt[0] = cur[0]; nxt[1] = cur[1]; nxt[2] = cur[2];
        }

        float acc[10];
#pragma unroll
        for (int k = 0; k < 10; ++k) acc[k] = 0.f;
#pragma unroll
        for (int i = 0; i < 3; ++i) {
            const float xs0 = cur[i].x, xs1 = cur[i].y, xs2 = cur[i].z, xs3 = cur[i].w;
#pragma unroll
            for (int k = 0; k < 3; ++k) {
                acc[k] += xs0 * wN[i][0][k];
                acc[k] += xs1 * wN[i][1][k];
                acc[k] += xs2 * wN[i][2][k];
                acc[k] += xs3 * wN[i][3][k];
            }
#pragma unroll
            for (int k = 0; k < 7; ++k) {
                acc[3 + k] += xs0 * wU[i][0][k];
                acc[3 + k] += xs1 * wU[i][1][k];
                acc[3 + k] += xs2 * wU[i][2][k];
                acc[3 + k] += xs3 * wU[i][3][k];
            }
        }
#pragma unroll
        for (int off = 32; off >= 1; off >>= 1) {
#pragma unroll
            for (int k = 0; k < 10; ++k)
                acc[k] += __shfl_xor(acc[k], off, 64);
        }
        const float zt0 = acc[0] + bn[0];
        const float zt1 = acc[1] + bn[1];
        const float zt2 = acc[2] + bn[2];
        const float mx = fmaxf(zt0, fmaxf(zt1, zt2));
        const float e0 = __expf(zt0 - mx);
        const float e1 = __expf(zt1 - mx);
        const float e2 = __expf(zt2 - mx);
        const float inv = 1.0f / (e0 + e1 + e2);
        const float p0 = e0 * inv, p1 = e1 * inv, p2 = e2 * inv;
        const float alpha = 0.5f * (p0 * p0 + p1 * p1 + p2 * p2);
        const float oma = 1.0f - alpha;
        float zst[7];
#pragma unroll
        for (int k = 0; k < 7; ++k) {
            const float zs  = acc[3 + k] + bu[k];
            const float zsp = zt0 * wt[0][k] + zt1 * wt[1][k] + zt2 * wt[2][k];
            zst[k] = zsp * alpha + zs * oma;
        }
        float vsel = zst[0];
#pragma unroll
        for (int k = 1; k < 7; ++k) vsel = (lane == k) ? zst[k] : vsel;
        if (lane < 7) zst_out[(size_t)row * 7 + lane] = vsel;
        const float vt = (lane == 8) ? zt1 : ((lane == 9) ? zt2 : zt0);
        if (lane >= 7 && lane < 10) zt_out[(size_t)row * 3 + (lane - 7)] = vt;

        cur[0] = nxt[0]; cur[1] = nxt[1]; cur[2] = nxt[2];
        row = nrow;
    }
}

// ---------------------------------------------------------------------------
// Kernel 2: one block per (b, crf). Phase A: 64-chunk log-semiring scans into
// LDS. Phase B: tree combine. Phase C: gold score + logZ, atomicAdd into loss.
// ---------------------------------------------------------------------------
template <int K>
__device__ void crf_block(
    const float* __restrict__ z,       // [T_SEQ][K] emissions for this b
    const int*   __restrict__ mask,    // [T_SEQ]
    const int*   __restrict__ labels,  // [T_SEQ]
    const float* __restrict__ trans, const float* __restrict__ startv,
    const float* __restrict__ endv,
    float* __restrict__ loss,
    float* bufA, float* bufB, float* red, float* redm)
{
    const int tid = threadIdx.x;
    const int KK = K * K;

    // ---- Phase A: chunk scans (t = 1 + 8c .. min(+8, 512)) ----
    for (int task = tid; task < 64 * K; task += 256) {
        const int c = task / K;
        const int irow = task % K;
        float E[K][K];
#pragma unroll
        for (int i = 0; i < K; ++i)
#pragma unroll
            for (int j = 0; j < K; ++j) E[i][j] = __expf(trans[i * K + j]);
        float a[K];
#pragma unroll
        for (int j = 0; j < K; ++j) a[j] = (j == irow) ? 0.f : NEGI;
        const int t0 = 1 + c * 8;
        int t1 = t0 + 8;
        if (t1 > T_SEQ) t1 = T_SEQ;
        for (int t = t0; t < t1; ++t) {
            if (mask[t]) {
                float m = a[0];
#pragma unroll
                for (int i = 1; i < K; ++i) m = fmaxf(m, a[i]);
                float ea[K];
#pragma unroll
                for (int i = 0; i < K; ++i) ea[i] = __expf(a[i] - m);
                float na[K];
#pragma unroll
                for (int j = 0; j < K; ++j) {
                    float s = 0.f;
#pragma unroll
                    for (int i = 0; i < K; ++i) s += ea[i] * E[i][j];
                    na[j] = z[t * K + j] + m + __logf(s);
                }
#pragma unroll
                for (int j = 0; j < K; ++j) a[j] = na[j];
            }
        }
#pragma unroll
        for (int j = 0; j < K; ++j) bufA[c * KK + irow * K + j] = a[j];
    }
    __syncthreads();

    // ---- Phase B: tree combine 64 matrices -> 1 ----
    float* src = bufA;
    float* dst = bufB;
    int n = 64;
    while (n > 1) {
        const int half = n >> 1;
        const int tasks = half * KK;
        for (int task = tid; task < tasks; task += 256) {
            const int p = task / KK;
            const int ij = task % KK;
            const int i = ij / K, j = ij % K;
            const float* A  = src + (size_t)(2 * p) * KK;
            const float* Bm = src + (size_t)(2 * p + 1) * KK;
            float m = A[i * K + 0] + Bm[0 * K + j];
#pragma unroll
            for (int k = 1; k < K; ++k) m = fmaxf(m, A[i * K + k] + Bm[k * K + j]);
            float s = 0.f;
#pragma unroll
            for (int k = 0; k < K; ++k) s += __expf(A[i * K + k] + Bm[k * K + j] - m);
            dst[task] = m + __logf(s);
        }
        __syncthreads();
        float* tmp = src; src = dst; dst = tmp;
        n = half;
    }

    // ---- Phase C: gold-path score + logZ ----
    float local_s = 0.f, local_m = 0.f;
    for (int t = tid; t < T_SEQ; t += 256) {
        const float mf = (float)mask[t];
        const int tg = labels[t];
        local_s += mf * z[t * K + tg];
        local_m += mf;
        if (t >= 1) {
            const int tp = labels[t - 1];
            local_s += mf * trans[tp * K + tg];
        }
    }
    red[tid] = local_s;
    redm[tid] = local_m;
    __syncthreads();
    for (int s = 128; s >= 1; s >>= 1) {
        if (tid < s) { red[tid] += red[tid + s]; redm[tid] += redm[tid + s]; }
        __syncthreads();
    }
    if (tid == 0) {
        float score = red[0];
        const int nvalid = (int)(redm[0] + 0.5f);
        const int last = nvalid - 1;
        score += startv[labels[0]] + endv[labels[last]];

        float alpha0[K];
#pragma unroll
        for (int i = 0; i < K; ++i) alpha0[i] = startv[i] + z[i];
        float v[K];
#pragma unroll
        for (int j = 0; j < K; ++j) {
            float m = alpha0[0] + src[0 * K + j];
#pragma unroll
            for (int i = 1; i < K; ++i) m = fmaxf(m, alpha0[i] + src[i * K + j]);
            float s = 0.f;
#pragma unroll
            for (int i = 0; i < K; ++i) s += __expf(alpha0[i] + src[i * K + j] - m);
            v[j] = m + __logf(s) + endv[j];
        }
        float mm = v[0];
#pragma unroll
        for (int j = 1; j < K; ++j) mm = fmaxf(mm, v[j]);
        float ss = 0.f;
#pragma unroll
        for (int j = 0; j < K; ++j) ss += __expf(v[j] - mm);
        const float logZ = mm + __logf(ss);
        atomicAdd(loss, logZ - score);   // loss = -sum(score - logZ)
    }
}

__global__ __launch_bounds__(256) void k2_crf(
    const float* __restrict__ zst, const float* __restrict__ zt,
    const int* __restrict__ mask, const int* __restrict__ labels,
    const int* __restrict__ labels_n,
    const float* __restrict__ trans_s, const float* __restrict__ start_s,
    const float* __restrict__ end_s,
    const float* __restrict__ trans_n, const float* __restrict__ start_n,
    const float* __restrict__ end_n,
    float* __restrict__ loss)
{
    __shared__ float bufA[64 * 49];
    __shared__ float bufB[32 * 49];
    __shared__ float red[256];
    __shared__ float redm[256];
    const int b = blockIdx.x & 63;
    if (blockIdx.x < 64) {
        crf_block<3>(zt + (size_t)b * T_SEQ * 3, mask + b * T_SEQ,
                     labels_n + b * T_SEQ, trans_n, start_n, end_n,
                     loss, bufA, bufB, red, redm);
    } else {
        crf_block<7>(zst + (size_t)b * T_SEQ * 7, mask + b * T_SEQ,
                     labels + b * T_SEQ, trans_s, start_s, end_s,
                     loss, bufA, bufB, red, redm);
    }
}

// ---------------------------------------------------------------------------
extern "C" void kernel_launch(void* const* d_in, const int* in_sizes, int n_in,
                              void* d_out, int out_size, void* d_ws, size_t ws_size,
                              hipStream_t stream)
{
    const float* x        = (const float*)d_in[0];
    const int*   mask     = (const int*)d_in[1];
    const int*   labels   = (const int*)d_in[2];
    const int*   labels_n = (const int*)d_in[3];
    const float* w_normal = (const float*)d_in[4];
    const float* b_normal = (const float*)d_in[5];
    const float* w_upper  = (const float*)d_in[6];
    const float* b_upper  = (const float*)d_in[7];
    const float* trans_n  = (const float*)d_in[8];
    const float* start_n  = (const float*)d_in[9];
    const float* end_n    = (const float*)d_in[10];
    const float* trans_s  = (const float*)d_in[11];
    const float* start_s  = (const float*)d_in[12];
    const float* end_s    = (const float*)d_in[13];
    const float* w_trans  = (const float*)d_in[14];

    float* out      = (float*)d_out;
    float* loss_out = out;       // [1]
    float* zst      = out + 1;   // [B*T*7]
    float* zt       = (float*)d_ws;  // [B*T*3]

    k1_fused_linear<<<K1_BLOCKS, 256, 0, stream>>>(x, w_normal, b_normal,
                                                   w_upper, b_upper, w_trans,
                                                   zst, zt, loss_out);
    k2_crf<<<128, 256, 0, stream>>>(zst, zt, mask, labels, labels_n,
                                    trans_s, start_s, end_s,
                                    trans_n, start_n, end_n, loss_out);
}